// Round 2
// baseline (274.122 us; speedup 1.0000x reference)
//
#include <hip/hip_runtime.h>
#include <math.h>

#define B_ 16
#define SEQ_ 8192
#define C_ 192
#define H_ 16
#define OV_ 4
#define G_ 6
#define K_ 1024
#define D_ 8
#define DG_ 2048
#define W_ 512
#define T_ 128
#define TT 2
#define OUT_ELEMS (B_ * SEQ_ * C_)   // 25165824

// workspace layout:
//   pd_perm : float [G*DG*D]  = 98304 floats   @ byte 0
//   pu_perm : float [G*D*DG]  = 98304 floats   @ byte 393216
//   cbn_d   : double[G*K*D]   = 49152 doubles  @ byte 786432
// d' = h*128 + ul  <->  group-local d = ul*16 + h,  u = g*128 + ul = o*192 + c

__global__ __launch_bounds__(256) void vq_prep(
    const float* __restrict__ pd, const float* __restrict__ pu,
    const float* __restrict__ cb,
    float* __restrict__ pd_p, float* __restrict__ pu_p,
    double* __restrict__ cbn, float* __restrict__ loss_slots)
{
  int i = blockIdx.x * 256 + threadIdx.x;
  if (i < 98304) {                       // pd_perm[g][d'][e]
    int e = i & 7, dp = (i >> 3) & 2047, g = i >> 14;
    int h = dp >> 7, ul = dp & 127, d = (ul << 4) + h;
    pd_p[i] = pd[(g << 14) + (d << 3) + e];
  } else if (i < 196608) {               // pu_perm[g][e][d']
    int i2 = i - 98304;
    int dp = i2 & 2047, e = (i2 >> 11) & 7, g = i2 >> 14;
    int h = dp >> 7, ul = dp & 127, d = (ul << 4) + h;
    pu_p[i2] = pu[(g << 14) + (e << 11) + d];
  } else if (i < 202752) {               // normalized codebooks, fp64
    int j = i - 196608;                  // j = g*1024 + k
    const float* row = cb + (j << 3);
    double ss = 0.0;
    #pragma unroll
    for (int e = 0; e < 8; ++e) { double x = (double)row[e]; ss += x * x; }
    double inv = 1.0 / fmax(sqrt(ss), 1e-12);
    #pragma unroll
    for (int e = 0; e < 8; ++e) cbn[(j << 3) + e] = (double)row[e] * inv;
  } else if (i < 202784) {               // zero the 32 loss accumulators
    loss_slots[i - 202752] = 0.0f;
  }
}

__global__ __launch_bounds__(256) void vq_main(
    const float* __restrict__ z, const float* __restrict__ cb,
    const float* __restrict__ pd_p, const float* __restrict__ pu_p,
    const double* __restrict__ cbn,
    float* __restrict__ out, float* __restrict__ loss_slots)
{
  __shared__ __align__(16) double red[8 * 256];   // 16 KB reduction buffer
  __shared__ double ze_d[TT * 8];
  __shared__ float  zq_s[TT * 8];
  __shared__ double wr_s[4][TT];
  __shared__ int    wr_k[4][TT];
  __shared__ float  lossv[TT];

  const int tid = threadIdx.x;
  const int tc  = blockIdx.x;   // 0..63 (chunk of TT=2 grouped frames)
  const int g   = blockIdx.y;   // 0..5
  const int b   = blockIdx.z;   // 0..15

  const float* zb = z + (size_t)b * (SEQ_ * C_);

  // ---------- phase 1: fused z load (global, float4) + fp64 partial dots ----------
  double acc[TT][8];
  #pragma unroll
  for (int t = 0; t < TT; ++t)
    #pragma unroll
    for (int e = 0; e < 8; ++e) acc[t][e] = 0.0;

  #pragma unroll
  for (int j = 0; j < 2; ++j) {
    int v   = j * 256 + tid;           // float4 slot 0..511
    int h   = v >> 5;
    int ul4 = (v & 31) << 2;
    int u   = (g << 7) + ul4;
    int o   = (u * 683) >> 17;         // u/192 for u<768
    int c   = u - o * 192;
    int dp  = (h << 7) + ul4;          // d' base for these 4 dims
    const float4* pdp = (const float4*)(pd_p + (((size_t)(g << 11) + dp) << 3));
    float4 p[8];                       // p[2r], p[2r+1] = 8 proj coeffs of dim dp+r
    #pragma unroll
    for (int r = 0; r < 8; ++r) p[r] = pdp[r];
    #pragma unroll
    for (int t = 0; t < TT; ++t) {
      int w = ((tc * TT + t) << 2) + o;
      float4 zv = *(const float4*)(zb + (size_t)(h * 512 + w) * 192 + c);
      float zc[4] = {zv.x, zv.y, zv.z, zv.w};
      #pragma unroll
      for (int r = 0; r < 4; ++r) {
        double zd = (double)zc[r];
        acc[t][0] = fma(zd, (double)p[2*r].x,   acc[t][0]);
        acc[t][1] = fma(zd, (double)p[2*r].y,   acc[t][1]);
        acc[t][2] = fma(zd, (double)p[2*r].z,   acc[t][2]);
        acc[t][3] = fma(zd, (double)p[2*r].w,   acc[t][3]);
        acc[t][4] = fma(zd, (double)p[2*r+1].x, acc[t][4]);
        acc[t][5] = fma(zd, (double)p[2*r+1].y, acc[t][5]);
        acc[t][6] = fma(zd, (double)p[2*r+1].z, acc[t][6]);
        acc[t][7] = fma(zd, (double)p[2*r+1].w, acc[t][7]);
      }
    }
  }

  // ---------- phase 1.5: reduce 16 (t,e) sums over 256 threads ----------
  #pragma unroll
  for (int r2 = 0; r2 < 2; ++r2) {
    if (r2) __syncthreads();
    #pragma unroll
    for (int kkl = 0; kkl < 8; ++kkl) {
      int kk = r2 * 8 + kkl;                     // kk = t*8 + e
      red[kkl * 256 + tid] = acc[kk >> 3][kk & 7];
    }
    __syncthreads();
    int kkl = tid >> 5, jj = tid & 31;
    double partial = 0.0;
    #pragma unroll
    for (int s = 0; s < 8; ++s)
      partial += red[kkl * 256 + s * 32 + jj];   // stride-32 doubles: 2-way, free
    partial += __shfl_down(partial, 16, 32);
    partial += __shfl_down(partial, 8, 32);
    partial += __shfl_down(partial, 4, 32);
    partial += __shfl_down(partial, 2, 32);
    partial += __shfl_down(partial, 1, 32);
    if (jj == 0) ze_d[r2 * 8 + kkl] = partial;
  }
  __syncthreads();

  // ---------- phase 2: argmax over 1024 codes (fp64 sim, first-max tie-break) ----------
  double zr[TT][8];
  #pragma unroll
  for (int t = 0; t < TT; ++t)
    #pragma unroll
    for (int e = 0; e < 8; ++e) zr[t][e] = ze_d[t * 8 + e];

  double bs[TT]; int bk[TT];
  #pragma unroll
  for (int t = 0; t < TT; ++t) { bs[t] = -1.0e300; bk[t] = 0x7fffffff; }
  #pragma unroll
  for (int q = 0; q < 4; ++q) {
    const double* cr = cbn + (((size_t)(g << 10) + (q << 8) + tid) << 3);
    double cdv[8];
    #pragma unroll
    for (int e = 0; e < 8; ++e) cdv[e] = cr[e];
    int k = (q << 8) + tid;            // ascending within thread -> strict > keeps min k
    #pragma unroll
    for (int t = 0; t < TT; ++t) {
      double s = 0.0;
      #pragma unroll
      for (int e = 0; e < 8; ++e) s = fma(zr[t][e], cdv[e], s);
      if (s > bs[t]) { bs[t] = s; bk[t] = k; }
    }
  }
  #pragma unroll
  for (int m = 32; m >= 1; m >>= 1) {
    #pragma unroll
    for (int t = 0; t < TT; ++t) {
      double os = __shfl_xor(bs[t], m);
      int    ok = __shfl_xor(bk[t], m);
      if (os > bs[t] || (os == bs[t] && ok < bk[t])) { bs[t] = os; bk[t] = ok; }
    }
  }
  int wv = tid >> 6;
  if ((tid & 63) == 0) {
    #pragma unroll
    for (int t = 0; t < TT; ++t) { wr_s[wv][t] = bs[t]; wr_k[wv][t] = bk[t]; }
  }
  __syncthreads();
  if (tid < TT) {
    int t = tid;
    double s0 = wr_s[0][t]; int k0 = wr_k[0][t];
    #pragma unroll
    for (int w2 = 1; w2 < 4; ++w2) {
      double s1 = wr_s[w2][t]; int k1 = wr_k[w2][t];
      if (s1 > s0 || (s1 == s0 && k1 < k0)) { s0 = s1; k0 = k1; }
    }
    const float* crow = cb + (((size_t)(g << 10) + k0) << 3);   // RAW codebook row
    double l = 0.0;
    #pragma unroll
    for (int e = 0; e < 8; ++e) {
      float qv = crow[e];
      zq_s[t * 8 + e] = qv;
      double dd = ze_d[t * 8 + e] - (double)qv;
      l = fma(dd, dd, l);
    }
    lossv[t] = (float)l;
  }
  __syncthreads();
  if (tid == 0) {
    float l = (lossv[0] + lossv[1]) * (1.0f / (T_ * D_ * G_));
    atomicAdd(loss_slots + b, l);        // commitment
    atomicAdd(loss_slots + 16 + b, l);   // codebook loss (numerically identical)
  }

  // ---------- phase 3: out = z_q @ proj_up, float4 coalesced stores ----------
  float zqr[TT][8];
  #pragma unroll
  for (int t = 0; t < TT; ++t)
    #pragma unroll
    for (int e = 0; e < 8; ++e) zqr[t][e] = zq_s[t * 8 + e];

  #pragma unroll
  for (int j = 0; j < 2; ++j) {
    int v   = j * 256 + tid;
    int h   = v >> 5;
    int ul4 = (v & 31) << 2;
    int u   = (g << 7) + ul4;
    int o   = (u * 683) >> 17;
    int c   = u - o * 192;
    int dp  = (h << 7) + ul4;
    float4 pu4[8];
    #pragma unroll
    for (int e = 0; e < 8; ++e)
      pu4[e] = *(const float4*)(pu_p + (size_t)(g << 14) + (e << 11) + dp);
    #pragma unroll
    for (int t = 0; t < TT; ++t) {
      float4 ov;
      ov.x = 0.f; ov.y = 0.f; ov.z = 0.f; ov.w = 0.f;
      #pragma unroll
      for (int e = 0; e < 8; ++e) {
        float zq = zqr[t][e];
        ov.x = fmaf(zq, pu4[e].x, ov.x);
        ov.y = fmaf(zq, pu4[e].y, ov.y);
        ov.z = fmaf(zq, pu4[e].z, ov.z);
        ov.w = fmaf(zq, pu4[e].w, ov.w);
      }
      int w = ((tc * TT + t) << 2) + o;
      *(float4*)(out + ((size_t)(b * SEQ_) + h * 512 + w) * 192 + c) = ov;
    }
  }
}

extern "C" void kernel_launch(void* const* d_in, const int* in_sizes, int n_in,
                              void* d_out, int out_size, void* d_ws, size_t ws_size,
                              hipStream_t stream)
{
  const float* z  = (const float*)d_in[0];   // (B, SEQ, C)
  const float* pd = (const float*)d_in[1];   // (G, DG, D)
  const float* pu = (const float*)d_in[2];   // (G, D, DG)
  const float* cb = (const float*)d_in[3];   // (G, K, D)
  float* out = (float*)d_out;
  float* loss_slots = out + OUT_ELEMS;       // 16 commitment + 16 codebook

  float*  pd_p = (float*)d_ws;
  float*  pu_p = pd_p + 98304;
  double* cbn  = (double*)(pu_p + 98304);

  vq_prep<<<793, 256, 0, stream>>>(pd, pu, cb, pd_p, pu_p, cbn, loss_slots);
  dim3 grid(T_ / TT, G_, B_);
  vq_main<<<grid, 256, 0, stream>>>(z, cb, pd_p, pu_p, cbn, out, loss_slots);
}

// Round 3
// 228.244 us; speedup vs baseline: 1.2010x; 1.2010x over previous
//
#include <hip/hip_runtime.h>
#include <math.h>

#define B_ 16
#define SEQ_ 8192
#define C_ 192
#define H_ 16
#define OV_ 4
#define G_ 6
#define K_ 1024
#define D_ 8
#define DG_ 2048
#define W_ 512
#define T_ 128
#define TT 16          // frames per block
#define NCH 8          // chunks of 2 frames
#define NT 512         // threads per block
#define OUT_ELEMS (B_ * SEQ_ * C_)   // 25165824

// workspace layout:
//   pd_perm : float [G*DG*D]  = 98304 floats   @ byte 0
//   pu_perm : float [G*D*DG]  = 98304 floats   @ byte 393216
//   cbn_d   : double[G*K*D]   = 49152 doubles  @ byte 786432
// d' = h*128 + ul  <->  group-local d = ul*16 + h,  u = g*128 + ul = o*192 + c

__global__ __launch_bounds__(256) void vq_prep(
    const float* __restrict__ pd, const float* __restrict__ pu,
    const float* __restrict__ cb,
    float* __restrict__ pd_p, float* __restrict__ pu_p,
    double* __restrict__ cbn, float* __restrict__ loss_slots)
{
  int i = blockIdx.x * 256 + threadIdx.x;
  if (i < 98304) {                       // pd_perm[g][d'][e]
    int e = i & 7, dp = (i >> 3) & 2047, g = i >> 14;
    int h = dp >> 7, ul = dp & 127, d = (ul << 4) + h;
    pd_p[i] = pd[(g << 14) + (d << 3) + e];
  } else if (i < 196608) {               // pu_perm[g][e][d']
    int i2 = i - 98304;
    int dp = i2 & 2047, e = (i2 >> 11) & 7, g = i2 >> 14;
    int h = dp >> 7, ul = dp & 127, d = (ul << 4) + h;
    pu_p[i2] = pu[(g << 14) + (e << 11) + d];
  } else if (i < 202752) {               // normalized codebooks, fp64
    int j = i - 196608;                  // j = g*1024 + k
    const float* row = cb + (j << 3);
    double ss = 0.0;
    #pragma unroll
    for (int e = 0; e < 8; ++e) { double x = (double)row[e]; ss += x * x; }
    double inv = 1.0 / fmax(sqrt(ss), 1e-12);
    #pragma unroll
    for (int e = 0; e < 8; ++e) cbn[(j << 3) + e] = (double)row[e] * inv;
  } else if (i < 202784) {               // zero the 32 loss accumulators
    loss_slots[i - 202752] = 0.0f;
  }
}

__global__ __launch_bounds__(NT, 2) void vq_main(
    const float* __restrict__ z, const float* __restrict__ cb,
    const float* __restrict__ pd_p, const float* __restrict__ pu_p,
    const double* __restrict__ cbn,
    float* __restrict__ out, float* __restrict__ loss_slots)
{
  __shared__ __align__(16) double red[16 * NT];   // 64 KB transpose-reduce buffer
  __shared__ double ze_d[TT * 8];                 // fp64 z_e per frame
  __shared__ float  zq_s[TT * 8];                 // chosen raw code rows
  __shared__ double cand_s[TT][8];                // per-wave argmax candidates
  __shared__ int    cand_k[TT][8];
  __shared__ float  lossv[TT];

  const int tid = threadIdx.x;
  const int tc  = blockIdx.x;   // 0..7  (16-frame chunk)
  const int g   = blockIdx.y;   // 0..5
  const int b   = blockIdx.z;   // 0..15

  const int h   = tid >> 5;
  const int ul4 = (tid & 31) << 2;
  const int u   = (g << 7) + ul4;
  const int o   = (u * 683) >> 17;     // u/192 for u<768
  const int c   = u - o * 192;

  // ---- persistent params: read ONCE per block ----
  // proj_down coeffs for this thread's 4 dims (dp = 4*tid .. 4*tid+3)
  const float4* pdp = (const float4*)(pd_p + (((size_t)(g << 11) + (tid << 2)) << 3));
  float4 p[8];
  #pragma unroll
  for (int r = 0; r < 8; ++r) p[r] = pdp[r];    // p[2m],p[2m+1] = dim 4*tid+m

  // this thread's 2 codebook rows (fp64-normalized): k = tid and 512+tid
  double cdv[2][8];
  #pragma unroll
  for (int q = 0; q < 2; ++q) {
    const double* cr = cbn + (((size_t)(g << 10) + (q << 9) + tid) << 3);
    #pragma unroll
    for (int e = 0; e < 8; ++e) cdv[q][e] = cr[e];
  }

  const float* zrow  = z + ((size_t)b * SEQ_ + h * 512) * 192 + c;
  const int    wbase = (tc << 6) + o;  // w of local frame 0

  float4 zv[2], zn[2];
  #pragma unroll
  for (int r = 0; r < 2; ++r)
    zv[r] = *(const float4*)(zrow + (size_t)(wbase + (r << 2)) * 192);

  for (int ch = 0; ch < NCH; ++ch) {
    // prefetch next chunk's z (dup-load on last chunk; L1-hot, harmless)
    const int chn = (ch < NCH - 1) ? ch + 1 : ch;
    #pragma unroll
    for (int r = 0; r < 2; ++r)
      zn[r] = *(const float4*)(zrow + (size_t)(wbase + ((chn * 2 + r) << 2)) * 192);

    // ---- fp64 partial dots for 2 frames ----
    double acc[2][8];
    #pragma unroll
    for (int r = 0; r < 2; ++r)
      #pragma unroll
      for (int e = 0; e < 8; ++e) acc[r][e] = 0.0;
    #pragma unroll
    for (int r = 0; r < 2; ++r) {
      float zc[4] = {zv[r].x, zv[r].y, zv[r].z, zv[r].w};
      #pragma unroll
      for (int m = 0; m < 4; ++m) {
        double zd = (double)zc[m];
        acc[r][0] = fma(zd, (double)p[2*m].x,   acc[r][0]);
        acc[r][1] = fma(zd, (double)p[2*m].y,   acc[r][1]);
        acc[r][2] = fma(zd, (double)p[2*m].z,   acc[r][2]);
        acc[r][3] = fma(zd, (double)p[2*m].w,   acc[r][3]);
        acc[r][4] = fma(zd, (double)p[2*m+1].x, acc[r][4]);
        acc[r][5] = fma(zd, (double)p[2*m+1].y, acc[r][5]);
        acc[r][6] = fma(zd, (double)p[2*m+1].z, acc[r][6]);
        acc[r][7] = fma(zd, (double)p[2*m+1].w, acc[r][7]);
      }
    }

    // ---- block reduction: 16 sums over 512 threads, one round ----
    #pragma unroll
    for (int kk = 0; kk < 16; ++kk)
      red[kk * NT + tid] = acc[kk >> 3][kk & 7];
    __syncthreads();
    {
      int kk = tid >> 5, jj = tid & 31;
      double partial = 0.0;
      #pragma unroll
      for (int i = 0; i < 16; ++i)
        partial += red[kk * NT + i * 32 + jj];
      partial += __shfl_down(partial, 16, 32);
      partial += __shfl_down(partial, 8, 32);
      partial += __shfl_down(partial, 4, 32);
      partial += __shfl_down(partial, 2, 32);
      partial += __shfl_down(partial, 1, 32);
      if (jj == 0) ze_d[(ch * 2 + (kk >> 3)) * 8 + (kk & 7)] = partial;
    }
    __syncthreads();   // ze_d visible; red reads done (guards next chunk's writes)

    // ---- per-chunk argmax: 2 codes/thread, 2 frames ----
    double zr[2][8];
    #pragma unroll
    for (int r = 0; r < 2; ++r)
      #pragma unroll
      for (int e = 0; e < 8; ++e) zr[r][e] = ze_d[(ch * 2 + r) * 8 + e];
    double bs[2] = {-1.0e300, -1.0e300};
    int    bk[2] = {0x7fffffff, 0x7fffffff};
    #pragma unroll
    for (int q = 0; q < 2; ++q) {
      int k = (q << 9) + tid;          // ascending in q: strict > keeps min k
      #pragma unroll
      for (int r = 0; r < 2; ++r) {
        double s = 0.0;
        #pragma unroll
        for (int e = 0; e < 8; ++e) s = fma(zr[r][e], cdv[q][e], s);
        if (s > bs[r]) { bs[r] = s; bk[r] = k; }
      }
    }
    #pragma unroll
    for (int m = 32; m >= 1; m >>= 1) {
      #pragma unroll
      for (int r = 0; r < 2; ++r) {
        double os = __shfl_xor(bs[r], m);
        int    ok = __shfl_xor(bk[r], m);
        if (os > bs[r] || (os == bs[r] && ok < bk[r])) { bs[r] = os; bk[r] = ok; }
      }
    }
    if ((tid & 63) == 0) {
      int wv = tid >> 6;
      #pragma unroll
      for (int r = 0; r < 2; ++r) {
        cand_s[ch * 2 + r][wv] = bs[r];
        cand_k[ch * 2 + r][wv] = bk[r];
      }
    }
    zv[0] = zn[0]; zv[1] = zn[1];
  }

  // ---- resolve argmax per frame, fetch raw code rows, loss ----
  __syncthreads();
  if (tid < TT) {
    int t = tid;
    double s0 = cand_s[t][0]; int k0 = cand_k[t][0];
    #pragma unroll
    for (int w2 = 1; w2 < 8; ++w2) {
      double s1 = cand_s[t][w2]; int k1 = cand_k[t][w2];
      if (s1 > s0 || (s1 == s0 && k1 < k0)) { s0 = s1; k0 = k1; }
    }
    const float* crow = cb + (((size_t)(g << 10) + k0) << 3);   // RAW codebook row
    double l = 0.0;
    #pragma unroll
    for (int e = 0; e < 8; ++e) {
      float qv = crow[e];
      zq_s[t * 8 + e] = qv;
      double dd = ze_d[t * 8 + e] - (double)qv;
      l = fma(dd, dd, l);
    }
    lossv[t] = (float)l;
  }
  __syncthreads();
  if (tid == 0) {
    float l = 0.f;
    #pragma unroll
    for (int t = 0; t < TT; ++t) l += lossv[t];
    l *= (1.0f / (T_ * D_ * G_));
    atomicAdd(loss_slots + b, l);        // commitment
    atomicAdd(loss_slots + 16 + b, l);   // codebook loss (numerically identical)
  }

  // ---- phase 3: out = z_q @ proj_up, 16 float4 stores/thread ----
  float4 pu4[8];
  #pragma unroll
  for (int e = 0; e < 8; ++e)
    pu4[e] = *(const float4*)(pu_p + (size_t)(g << 14) + (e << 11) + (tid << 2));
  const size_t obase = ((size_t)b * SEQ_ + h * 512) * 192 + c;
  #pragma unroll
  for (int f = 0; f < TT; ++f) {
    float zq[8];
    #pragma unroll
    for (int e = 0; e < 8; ++e) zq[e] = zq_s[f * 8 + e];
    float4 ov; ov.x = 0.f; ov.y = 0.f; ov.z = 0.f; ov.w = 0.f;
    #pragma unroll
    for (int e = 0; e < 8; ++e) {
      ov.x = fmaf(zq[e], pu4[e].x, ov.x);
      ov.y = fmaf(zq[e], pu4[e].y, ov.y);
      ov.z = fmaf(zq[e], pu4[e].z, ov.z);
      ov.w = fmaf(zq[e], pu4[e].w, ov.w);
    }
    *(float4*)(out + obase + (size_t)(wbase + (f << 2)) * 192) = ov;
  }
}

extern "C" void kernel_launch(void* const* d_in, const int* in_sizes, int n_in,
                              void* d_out, int out_size, void* d_ws, size_t ws_size,
                              hipStream_t stream)
{
  const float* z  = (const float*)d_in[0];   // (B, SEQ, C)
  const float* pd = (const float*)d_in[1];   // (G, DG, D)
  const float* pu = (const float*)d_in[2];   // (G, D, DG)
  const float* cb = (const float*)d_in[3];   // (G, K, D)
  float* out = (float*)d_out;
  float* loss_slots = out + OUT_ELEMS;       // 16 commitment + 16 codebook

  float*  pd_p = (float*)d_ws;
  float*  pu_p = pd_p + 98304;
  double* cbn  = (double*)(pu_p + 98304);

  vq_prep<<<793, 256, 0, stream>>>(pd, pu, cb, pd_p, pu_p, cbn, loss_slots);
  dim3 grid(T_ / TT, G_, B_);
  vq_main<<<grid, NT, 0, stream>>>(z, cb, pd_p, pu_p, cbn, out, loss_slots);
}